// Round 8
// baseline (84.539 us; speedup 1.0000x reference)
//
#include <hip/hip_runtime.h>
#include <hip/hip_bf16.h>

typedef __bf16 bf16x8 __attribute__((ext_vector_type(8)));
typedef float f32x2 __attribute__((ext_vector_type(2)));
typedef float f32x4 __attribute__((ext_vector_type(4)));
typedef float f32x16 __attribute__((ext_vector_type(16)));

#define B_N 2048
#define O_N 2048
#define K_N 64

__device__ __forceinline__ void gld16(const void* g, void* l) {
    __builtin_amdgcn_global_load_lds(
        (const __attribute__((address_space(1))) void*)g,
        (__attribute__((address_space(3))) void*)l,
        16, 0, 0);
}

// ---------------------------------------------------------------------------
// prep (unchanged):
//   Atp[o]: A-op panel, element(ss,j,h,e) at ss*1024 + j*16 + h*8 + e
//           = bf16( inv[o][16ss+8h+e][j]^2 )          (8KB per o)
//   cPhi/cPlo: c = -(A^T+A)m in bf16 hi/lo, MFMA-A-frag layout (32-o groups)
//   kArr[o] = m^T A m (f32)
// ---------------------------------------------------------------------------
__global__ __launch_bounds__(256) void rbf_prep(
    const float* __restrict__ inv, const float* __restrict__ means,
    __bf16* __restrict__ Atp, __bf16* __restrict__ cPhi,
    __bf16* __restrict__ cPlo, float* __restrict__ kArr)
{
    __shared__ float s[64 * 65];
    __shared__ float mld[64];
    __shared__ float uw[128];
    const int o = blockIdx.x;
    const int t = threadIdx.x;
    const float4* src = (const float4*)(inv + (size_t)o * 4096);
#pragma unroll
    for (int k = 0; k < 4; ++k) {
        const int idx = k * 256 + t;
        const float4 v = src[idx];
        const int i = idx >> 4;
        const int j0 = (idx & 15) * 4;
        s[i * 65 + j0 + 0] = v.x * v.x;
        s[i * 65 + j0 + 1] = v.y * v.y;
        s[i * 65 + j0 + 2] = v.z * v.z;
        s[i * 65 + j0 + 3] = v.w * v.w;
    }
    if (t < 64) mld[t] = means[(size_t)t * O_N + o];
    __syncthreads();
    if (t < 64) {
        float u = 0.f;
#pragma unroll
        for (int i = 0; i < 64; ++i) u = fmaf(s[i * 65 + t], mld[i], u);
        uw[t] = u;
    } else if (t < 128) {
        const int j = t - 64;
        float w = 0.f;
#pragma unroll
        for (int i = 0; i < 64; ++i) w = fmaf(s[j * 65 + i], mld[i], w);
        uw[64 + j] = w;
    }
    __syncthreads();
    if (t < 64) {
        const float c = -(uw[t] + uw[64 + t]);
        const __bf16 hi = (__bf16)c;
        const __bf16 lo = (__bf16)(c - (float)hi);
        const size_t eidx = (size_t)(o >> 5) * 2048 + (size_t)(t >> 4) * 512
                          + (size_t)(o & 31) * 16 + (t & 15);
        cPhi[eidx] = hi;
        cPlo[eidx] = lo;
    }
    if (t == 0) {
        float kk = 0.f;
#pragma unroll
        for (int j = 0; j < 64; ++j) kk = fmaf(uw[j], mld[j], kk);
        kArr[o] = kk;
    }
#pragma unroll
    for (int r = 0; r < 2; ++r) {
        const int ch = r * 256 + t;
        const int ss = ch >> 7;
        const int j = (ch >> 1) & 63;
        const int hh = ch & 1;
        bf16x8 v;
#pragma unroll
        for (int e = 0; e < 8; ++e)
            v[e] = (__bf16)s[(16 * ss + 8 * hh + e) * 65 + j];
        *(bf16x8*)(Atp + (size_t)o * 4096 + (size_t)ch * 8) = v;
    }
}

// ---------------------------------------------------------------------------
// main: block = 128 rows x 32 o's; 4 waves x 32 rows; grid 1024, 4 blocks/CU.
// Pair-phases (2 o's per barrier), 4 LDS buffers. SOFTWARE PIPELINE: the
// last o of each pair keeps its accumulators (aP0,aP1) across the barrier;
// its dot/exp/store runs FIRST in the next pair, filling the post-barrier
// ds_read/MFMA-wait stall with independent VALU work.
// C-layout (32x32): col = lane&31, row = (reg&3)+8*(reg>>2)+4*(lane>>5);
// owner half of o=I is h = (I>>2)&1, lin register r(I) = (I&3)+((I>>3)<<2).
// ---------------------------------------------------------------------------
__global__ __launch_bounds__(256, 4) void rbf_main(
    const float* __restrict__ x, const __bf16* __restrict__ Atp,
    const __bf16* __restrict__ cPhi, const __bf16* __restrict__ cPlo,
    const float* __restrict__ kArr, float* __restrict__ out)
{
    __shared__ __align__(16) __bf16 sA[4][4096];

    const int tid = threadIdx.x;
    const int lane = tid & 63;
    const int b = lane & 31;
    const int h = lane >> 5;

    // 1024 blocks = 8 XCD x (8 og x 16 bg); per-XCD Atp slice = 2MB in its L2
    const int wg = (int)blockIdx.x;
    const int xcd = wg & 7;
    const int loc = wg >> 3;
    const int og = xcd * 8 + (loc >> 4);
    const int bg = loc & 15;
    const int oBase = og * 32;
    const int rowW = bg * 128 + (tid >> 6) * 32;

    const float* xr = x + (size_t)(rowW + b) * K_N;

    const f32x16 zz = {0.f,0.f,0.f,0.f,0.f,0.f,0.f,0.f,
                       0.f,0.f,0.f,0.f,0.f,0.f,0.f,0.f};

    // x bf16 B-op frags + f32 dot copies; lin(+k) computed into registers
    bf16x8 xh[4];
    f32x4 xd[2][4];
    f32x16 lin;
    {
        bf16x8 xl[4];
#pragma unroll
        for (int ss = 0; ss < 4; ++ss) {
            const float* p = xr + ss * 16 + h * 8;
            bf16x8 vh, vl;
#pragma unroll
            for (int e = 0; e < 8; ++e) {
                const float v = p[e];
                const __bf16 hi = (__bf16)v;
                vh[e] = hi;
                vl[e] = (__bf16)(v - (float)hi);
            }
            xh[ss] = vh; xl[ss] = vl;
        }
#pragma unroll
        for (int mt = 0; mt < 2; ++mt)
#pragma unroll
            for (int rq = 0; rq < 4; ++rq)
                xd[mt][rq] = *(const f32x4*)(xr + mt * 32 + rq * 8 + h * 4);

        const __bf16* chp = cPhi + (size_t)og * 2048;
        const __bf16* clp = cPlo + (size_t)og * 2048;
        lin = zz;
#pragma unroll
        for (int ss = 0; ss < 4; ++ss) {
            const bf16x8 fh = *(const bf16x8*)(chp + ss * 512 + b * 16 + h * 8);
            const bf16x8 fl = *(const bf16x8*)(clp + ss * 512 + b * 16 + h * 8);
            lin = __builtin_amdgcn_mfma_f32_32x32x16_bf16(fh, xh[ss], lin, 0, 0, 0);
            lin = __builtin_amdgcn_mfma_f32_32x32x16_bf16(fh, xl[ss], lin, 0, 0, 0);
            lin = __builtin_amdgcn_mfma_f32_32x32x16_bf16(fl, xh[ss], lin, 0, 0, 0);
        }
#pragma unroll
        for (int r = 0; r < 16; ++r)
            lin[r] += kArr[oBase + (r & 3) + 8 * (r >> 2) + 4 * h];
    }

    // staging: linear LDS dest, pre-swizzled global src (involution swz)
    const int L0 = tid * 16, L1 = 4096 + tid * 16;
    const int S0 = L0 ^ (((L0 >> 7) & 7) << 4);
    const int S1 = L1 ^ (((L1 >> 7) & 7) << 4);
    const char* gp = (const char*)(Atp + (size_t)oBase * 4096);
    gld16(gp + S0, (char*)&sA[0][0] + L0);           // panel 0
    gld16(gp + S1, (char*)&sA[0][0] + L1);
    gld16(gp + 8192 + S0, (char*)&sA[1][0] + L0);    // panel 1
    gld16(gp + 8192 + S1, (char*)&sA[1][0] + L1);

    const int off0 = (b * 32 + h * 16) ^ (((b >> 2) & 7) << 4);
    float* outp = out + (size_t)(rowW + b) * O_N + oBase;
    float q4[4];
    f32x16 a0, a1, aP0, aP1;

// dot + exp + (owner) store for o = I from accumulators (A0,A1)
#define RBF_DOT(A0, A1, I) do {                                               \
    f32x2 P0_ = {0.f, 0.f}, P1_ = {0.f, 0.f};                                 \
    _Pragma("unroll")                                                         \
    for (int rg = 0; rg < 4; ++rg) {                                          \
        f32x2 u_, v_;                                                         \
        u_[0] = (A0)[rg*4+0]; u_[1] = (A0)[rg*4+1];                           \
        v_[0] = xd[0][rg][0]; v_[1] = xd[0][rg][1];                           \
        P0_ = __builtin_elementwise_fma(u_, v_, P0_);                         \
        u_[0] = (A0)[rg*4+2]; u_[1] = (A0)[rg*4+3];                           \
        v_[0] = xd[0][rg][2]; v_[1] = xd[0][rg][3];                           \
        P1_ = __builtin_elementwise_fma(u_, v_, P1_);                         \
        u_[0] = (A1)[rg*4+0]; u_[1] = (A1)[rg*4+1];                           \
        v_[0] = xd[1][rg][0]; v_[1] = xd[1][rg][1];                           \
        P0_ = __builtin_elementwise_fma(u_, v_, P0_);                         \
        u_[0] = (A1)[rg*4+2]; u_[1] = (A1)[rg*4+3];                           \
        v_[0] = xd[1][rg][2]; v_[1] = xd[1][rg][3];                           \
        P1_ = __builtin_elementwise_fma(u_, v_, P1_);                         \
    }                                                                         \
    const f32x2 Ps_ = P0_ + P1_;                                              \
    float qh_ = Ps_[0] + Ps_[1];                                              \
    /* owner half folds in lin BEFORE the shfl so both halves see q+lin */    \
    qh_ += (h == (((I) >> 2) & 1)) ? lin[((I) & 3) + (((I) >> 3) << 2)] : 0.f;\
    const float q_ = qh_ + __shfl_xor(qh_, 32, 64);                           \
    q4[(I) & 3] = exp2f(q_ * -0.72134752044448170368f);                       \
    if (((I) & 3) == 3 && h == (((I) >> 2) & 1)) {                            \
        const f32x4 v_ = {q4[0], q4[1], q4[2], q4[3]};                        \
        *(f32x4*)(outp + ((I) - 3)) = v_;                                     \
    }                                                                         \
} while (0)

#define RBF_READS(G, BUF) do {                                                \
    _Pragma("unroll")                                                         \
    for (int ss = 0; ss < 4; ++ss) {                                          \
        (G)[2*ss]   = *(const bf16x8*)((BUF) + ss * 2048 + off0);             \
        (G)[2*ss+1] = *(const bf16x8*)((BUF) + ss * 2048 + 1024 + off0);      \
    }                                                                         \
} while (0)

#define RBF_MFMA(G, A0, A1) do {                                              \
    __builtin_amdgcn_s_setprio(1);                                            \
    (A0) = __builtin_amdgcn_mfma_f32_32x32x16_bf16((G)[0], xh[0], zz, 0, 0, 0); \
    (A1) = __builtin_amdgcn_mfma_f32_32x32x16_bf16((G)[1], xh[0], zz, 0, 0, 0); \
    _Pragma("unroll")                                                         \
    for (int ss = 1; ss < 4; ++ss) {                                          \
        (A0) = __builtin_amdgcn_mfma_f32_32x32x16_bf16((G)[2*ss],   xh[ss], (A0), 0, 0, 0); \
        (A1) = __builtin_amdgcn_mfma_f32_32x32x16_bf16((G)[2*ss+1], xh[ss], (A1), 0, 0, 0); \
    }                                                                         \
    __builtin_amdgcn_s_setprio(0);                                            \
} while (0)

// pair P: o0 = 2P, o1 = 2P+1.  Pipeline: DOT(o1 of pair P-1) runs first,
// under the ds_read latency of this pair's reads; MFMA(o1) carries out.
#define RBF_PAIR(P) do {                                                      \
    __syncthreads();                                                          \
    if ((P) < 15) {                                                           \
        const char* g2_ = gp + (size_t)(2 * (P) + 2) * 8192;                  \
        char* d2_ = (char*)&sA[(2 * (P) + 2) & 3][0];                         \
        gld16(g2_ + S0, d2_ + L0);                                            \
        gld16(g2_ + S1, d2_ + L1);                                            \
        const char* g3_ = gp + (size_t)(2 * (P) + 3) * 8192;                  \
        char* d3_ = (char*)&sA[(2 * (P) + 3) & 3][0];                         \
        gld16(g3_ + S0, d3_ + L0);                                            \
        gld16(g3_ + S1, d3_ + L1);                                            \
    }                                                                         \
    const char* b0_ = (const char*)&sA[(2 * (P)) & 3][0];                     \
    bf16x8 g0_[8];                                                            \
    RBF_READS(g0_, b0_);                                                      \
    if ((P) > 0) RBF_DOT(aP0, aP1, 2 * (P) - 1);                              \
    RBF_MFMA(g0_, a0, a1);                                                    \
    const char* b1_ = (const char*)&sA[(2 * (P) + 1) & 3][0];                 \
    bf16x8 g1_[8];                                                            \
    RBF_READS(g1_, b1_);                                                      \
    RBF_DOT(a0, a1, 2 * (P));                                                 \
    RBF_MFMA(g1_, aP0, aP1);                                                  \
} while (0)

    RBF_PAIR(0);  RBF_PAIR(1);  RBF_PAIR(2);  RBF_PAIR(3);
    RBF_PAIR(4);  RBF_PAIR(5);  RBF_PAIR(6);  RBF_PAIR(7);
    RBF_PAIR(8);  RBF_PAIR(9);  RBF_PAIR(10); RBF_PAIR(11);
    RBF_PAIR(12); RBF_PAIR(13); RBF_PAIR(14); RBF_PAIR(15);

    RBF_DOT(aP0, aP1, 31);   // epilogue: drain the carried o=31

#undef RBF_PAIR
#undef RBF_MFMA
#undef RBF_READS
#undef RBF_DOT
}

extern "C" void kernel_launch(void* const* d_in, const int* in_sizes, int n_in,
                              void* d_out, int out_size, void* d_ws, size_t ws_size,
                              hipStream_t stream)
{
    const float* x = (const float*)d_in[0];
    const float* means = (const float*)d_in[1];
    const float* inv = (const float*)d_in[2];
    float* out = (float*)d_out;

    char* w = (char*)d_ws;
    __bf16* Atp  = (__bf16*)w;                                     // 16.78 MB
    __bf16* cPhi = (__bf16*)(w + (size_t)O_N * 4096 * 2);          // 256 KB
    __bf16* cPlo = (__bf16*)(w + (size_t)O_N * 4096 * 2 + 262144); // 256 KB
    float*  kArr = (float*)(w + (size_t)O_N * 4096 * 2 + 524288);  // 8 KB

    rbf_prep<<<dim3(O_N), dim3(256), 0, stream>>>(inv, means, Atp, cPhi, cPlo, kArr);
    rbf_main<<<dim3(1024), dim3(256), 0, stream>>>(x, Atp, cPhi, cPlo, kArr, out);

    (void)in_sizes; (void)n_in; (void)out_size; (void)ws_size;
}

// Round 9
// 63.345 us; speedup vs baseline: 1.3346x; 1.3346x over previous
//
#include <hip/hip_runtime.h>
#include <hip/hip_bf16.h>

typedef __bf16 bf16x8 __attribute__((ext_vector_type(8)));
typedef float f32x2 __attribute__((ext_vector_type(2)));
typedef float f32x4 __attribute__((ext_vector_type(4)));
typedef float f32x16 __attribute__((ext_vector_type(16)));

#define B_N 2048
#define O_N 2048
#define K_N 64

__device__ __forceinline__ void gld16(const void* g, void* l) {
    __builtin_amdgcn_global_load_lds(
        (const __attribute__((address_space(1))) void*)g,
        (__attribute__((address_space(3))) void*)l,
        16, 0, 0);
}

// ---------------------------------------------------------------------------
// prep (unchanged):
//   Atp[o]: A-op panel, element(ss,j,h,e) at ss*1024 + j*16 + h*8 + e
//           = bf16( inv[o][16ss+8h+e][j]^2 )          (8KB per o)
//   cPhi/cPlo: c = -(A^T+A)m in bf16 hi/lo, MFMA-A-frag layout (32-o groups)
//   kArr[o] = m^T A m (f32)
// ---------------------------------------------------------------------------
__global__ __launch_bounds__(256) void rbf_prep(
    const float* __restrict__ inv, const float* __restrict__ means,
    __bf16* __restrict__ Atp, __bf16* __restrict__ cPhi,
    __bf16* __restrict__ cPlo, float* __restrict__ kArr)
{
    __shared__ float s[64 * 65];
    __shared__ float mld[64];
    __shared__ float uw[128];
    const int o = blockIdx.x;
    const int t = threadIdx.x;
    const float4* src = (const float4*)(inv + (size_t)o * 4096);
#pragma unroll
    for (int k = 0; k < 4; ++k) {
        const int idx = k * 256 + t;
        const float4 v = src[idx];
        const int i = idx >> 4;
        const int j0 = (idx & 15) * 4;
        s[i * 65 + j0 + 0] = v.x * v.x;
        s[i * 65 + j0 + 1] = v.y * v.y;
        s[i * 65 + j0 + 2] = v.z * v.z;
        s[i * 65 + j0 + 3] = v.w * v.w;
    }
    if (t < 64) mld[t] = means[(size_t)t * O_N + o];
    __syncthreads();
    if (t < 64) {
        float u = 0.f;
#pragma unroll
        for (int i = 0; i < 64; ++i) u = fmaf(s[i * 65 + t], mld[i], u);
        uw[t] = u;
    } else if (t < 128) {
        const int j = t - 64;
        float w = 0.f;
#pragma unroll
        for (int i = 0; i < 64; ++i) w = fmaf(s[j * 65 + i], mld[i], w);
        uw[64 + j] = w;
    }
    __syncthreads();
    if (t < 64) {
        const float c = -(uw[t] + uw[64 + t]);
        const __bf16 hi = (__bf16)c;
        const __bf16 lo = (__bf16)(c - (float)hi);
        const size_t eidx = (size_t)(o >> 5) * 2048 + (size_t)(t >> 4) * 512
                          + (size_t)(o & 31) * 16 + (t & 15);
        cPhi[eidx] = hi;
        cPlo[eidx] = lo;
    }
    if (t == 0) {
        float kk = 0.f;
#pragma unroll
        for (int j = 0; j < 64; ++j) kk = fmaf(uw[j], mld[j], kk);
        kArr[o] = kk;
    }
#pragma unroll
    for (int r = 0; r < 2; ++r) {
        const int ch = r * 256 + t;
        const int ss = ch >> 7;
        const int j = (ch >> 1) & 63;
        const int hh = ch & 1;
        bf16x8 v;
#pragma unroll
        for (int e = 0; e < 8; ++e)
            v[e] = (__bf16)s[(16 * ss + 8 * hh + e) * 65 + j];
        *(bf16x8*)(Atp + (size_t)o * 4096 + (size_t)ch * 8) = v;
    }
}

// ---------------------------------------------------------------------------
// main: block = 128 rows x 32 o's as 2 waves x 64 rows (2 row-tiles/wave:
// the 8KB panel read feeds 16 MFMAs -> LDS traffic per unit halved vs R7).
// Grid 1024 = 8 XCD x 8 og x 16 bg; 4 blocks/CU (LDS 32KB), 4 barrier
// groups. Pair-phases: 1 barrier per 2 o's, 4 LDS buffers. NO cross-barrier
// register carry (R8 spill lesson); acc pairs strictly scoped.
// C-layout (32x32): col = lane&31, row = (reg&3)+8*(reg>>2)+4*(lane>>5);
// owner half of o=I is h = (I>>2)&1, lin register r(I) = (I&3)+((I>>3)<<2).
// ---------------------------------------------------------------------------
__global__ __launch_bounds__(128, 2) void rbf_main(
    const float* __restrict__ x, const __bf16* __restrict__ Atp,
    const __bf16* __restrict__ cPhi, const __bf16* __restrict__ cPlo,
    const float* __restrict__ kArr, float* __restrict__ out)
{
    __shared__ __align__(16) __bf16 sA[4][4096];

    const int tid = threadIdx.x;            // 0..127
    const int wave = tid >> 6;
    const int lane = tid & 63;
    const int b = lane & 31;
    const int h = lane >> 5;

    // 1024 blocks = 8 XCD x (8 og x 16 bg); per-XCD Atp slice = 2MB in its L2
    const int wg = (int)blockIdx.x;
    const int xcd = wg & 7;
    const int loc = wg >> 3;
    const int og = xcd * 8 + (loc >> 4);
    const int bg = loc & 15;
    const int oBase = og * 32;
    const int rowW = bg * 128 + wave * 64;   // wave covers rows rowW..rowW+63

    const f32x16 zz = {0.f,0.f,0.f,0.f,0.f,0.f,0.f,0.f,
                       0.f,0.f,0.f,0.f,0.f,0.f,0.f,0.f};

    // per-tile x state: bf16 B-op frags, f32 dot copies, lin(+k) registers
    bf16x8 xh[2][4];
    f32x4 xd[2][2][4];
    f32x16 lin[2];
    {
        bf16x8 xl[2][4];
#pragma unroll
        for (int t = 0; t < 2; ++t) {
            const float* xr = x + (size_t)(rowW + t * 32 + b) * K_N;
#pragma unroll
            for (int ss = 0; ss < 4; ++ss) {
                const float* p = xr + ss * 16 + h * 8;
                bf16x8 vh, vl;
#pragma unroll
                for (int e = 0; e < 8; ++e) {
                    const float v = p[e];
                    const __bf16 hi = (__bf16)v;
                    vh[e] = hi;
                    vl[e] = (__bf16)(v - (float)hi);
                }
                xh[t][ss] = vh; xl[t][ss] = vl;
            }
#pragma unroll
            for (int mt = 0; mt < 2; ++mt)
#pragma unroll
                for (int rq = 0; rq < 4; ++rq)
                    xd[t][mt][rq] = *(const f32x4*)(xr + mt * 32 + rq * 8 + h * 4);
        }
        const __bf16* chp = cPhi + (size_t)og * 2048;
        const __bf16* clp = cPlo + (size_t)og * 2048;
        bf16x8 fh[4], fl[4];
#pragma unroll
        for (int ss = 0; ss < 4; ++ss) {
            fh[ss] = *(const bf16x8*)(chp + ss * 512 + b * 16 + h * 8);
            fl[ss] = *(const bf16x8*)(clp + ss * 512 + b * 16 + h * 8);
        }
#pragma unroll
        for (int t = 0; t < 2; ++t) {
            f32x16 l = zz;
#pragma unroll
            for (int ss = 0; ss < 4; ++ss) {
                l = __builtin_amdgcn_mfma_f32_32x32x16_bf16(fh[ss], xh[t][ss], l, 0, 0, 0);
                l = __builtin_amdgcn_mfma_f32_32x32x16_bf16(fh[ss], xl[t][ss], l, 0, 0, 0);
                l = __builtin_amdgcn_mfma_f32_32x32x16_bf16(fl[ss], xh[t][ss], l, 0, 0, 0);
            }
            lin[t] = l;
        }
#pragma unroll
        for (int r = 0; r < 16; ++r) {
            const float ka = kArr[oBase + (r & 3) + 8 * (r >> 2) + 4 * h];
            lin[0][r] += ka;
            lin[1][r] += ka;
        }
    }

    // staging: linear LDS dest, pre-swizzled global src; 128 thr x 4 chunks
    const int Xr = ((tid >> 3) & 7) << 4;     // swizzle XOR bits (chunk-invt)
    const int Lb = tid * 16;
    const char* gp = (const char*)(Atp + (size_t)oBase * 4096);

#define RBF_STAGE(PANEL) do {                                                 \
    const char* g_ = gp + (size_t)(PANEL) * 8192;                             \
    char* d_ = (char*)&sA[(PANEL) & 3][0];                                    \
    _Pragma("unroll")                                                         \
    for (int c_ = 0; c_ < 4; ++c_) {                                          \
        const int L_ = c_ * 2048 + Lb;                                        \
        gld16(g_ + (L_ ^ Xr), d_ + L_);                                       \
    }                                                                         \
} while (0)

    RBF_STAGE(0);
    RBF_STAGE(1);

    const int off0 = (b * 32 + h * 16) ^ (((b >> 2) & 7) << 4);
    float* outp0 = out + (size_t)(rowW + b) * O_N + oBase;
    float* outp1 = out + (size_t)(rowW + 32 + b) * O_N + oBase;
    float q4[2][4];

#define RBF_READS(G, BUF) do {                                                \
    _Pragma("unroll")                                                         \
    for (int ss = 0; ss < 4; ++ss) {                                          \
        (G)[2*ss]   = *(const bf16x8*)((BUF) + ss * 2048 + off0);             \
        (G)[2*ss+1] = *(const bf16x8*)((BUF) + ss * 2048 + 1024 + off0);      \
    }                                                                         \
} while (0)

// both tiles' MFMAs from one set of panel fragments G
#define RBF_MFMA2(G, A0, A1, B0, B1) do {                                     \
    __builtin_amdgcn_s_setprio(1);                                            \
    (A0) = __builtin_amdgcn_mfma_f32_32x32x16_bf16((G)[0], xh[0][0], zz, 0, 0, 0); \
    (A1) = __builtin_amdgcn_mfma_f32_32x32x16_bf16((G)[1], xh[0][0], zz, 0, 0, 0); \
    (B0) = __builtin_amdgcn_mfma_f32_32x32x16_bf16((G)[0], xh[1][0], zz, 0, 0, 0); \
    (B1) = __builtin_amdgcn_mfma_f32_32x32x16_bf16((G)[1], xh[1][0], zz, 0, 0, 0); \
    _Pragma("unroll")                                                         \
    for (int ss = 1; ss < 4; ++ss) {                                          \
        (A0) = __builtin_amdgcn_mfma_f32_32x32x16_bf16((G)[2*ss],   xh[0][ss], (A0), 0, 0, 0); \
        (A1) = __builtin_amdgcn_mfma_f32_32x32x16_bf16((G)[2*ss+1], xh[0][ss], (A1), 0, 0, 0); \
        (B0) = __builtin_amdgcn_mfma_f32_32x32x16_bf16((G)[2*ss],   xh[1][ss], (B0), 0, 0, 0); \
        (B1) = __builtin_amdgcn_mfma_f32_32x32x16_bf16((G)[2*ss+1], xh[1][ss], (B1), 0, 0, 0); \
    }                                                                         \
    __builtin_amdgcn_s_setprio(0);                                            \
} while (0)

// dot + exp + (owner) store for o = I, tile T, from accumulators (A0,A1)
#define RBF_DOT(A0, A1, I, T, OUTP) do {                                      \
    f32x2 P0_ = {0.f, 0.f}, P1_ = {0.f, 0.f};                                 \
    _Pragma("unroll")                                                         \
    for (int rg = 0; rg < 4; ++rg) {                                          \
        f32x2 u_, v_;                                                         \
        u_[0] = (A0)[rg*4+0]; u_[1] = (A0)[rg*4+1];                           \
        v_[0] = xd[T][0][rg][0]; v_[1] = xd[T][0][rg][1];                     \
        P0_ = __builtin_elementwise_fma(u_, v_, P0_);                         \
        u_[0] = (A0)[rg*4+2]; u_[1] = (A0)[rg*4+3];                           \
        v_[0] = xd[T][0][rg][2]; v_[1] = xd[T][0][rg][3];                     \
        P1_ = __builtin_elementwise_fma(u_, v_, P1_);                         \
        u_[0] = (A1)[rg*4+0]; u_[1] = (A1)[rg*4+1];                           \
        v_[0] = xd[T][1][rg][0]; v_[1] = xd[T][1][rg][1];                     \
        P0_ = __builtin_elementwise_fma(u_, v_, P0_);                         \
        u_[0] = (A1)[rg*4+2]; u_[1] = (A1)[rg*4+3];                           \
        v_[0] = xd[T][1][rg][2]; v_[1] = xd[T][1][rg][3];                     \
        P1_ = __builtin_elementwise_fma(u_, v_, P1_);                         \
    }                                                                         \
    const f32x2 Ps_ = P0_ + P1_;                                              \
    float qh_ = Ps_[0] + Ps_[1];                                              \
    qh_ += (h == (((I) >> 2) & 1)) ? lin[T][((I) & 3) + (((I) >> 3) << 2)] : 0.f; \
    const float q_ = qh_ + __shfl_xor(qh_, 32, 64);                           \
    q4[T][(I) & 3] = exp2f(q_ * -0.72134752044448170368f);                    \
    if (((I) & 3) == 3 && h == (((I) >> 2) & 1)) {                            \
        const f32x4 v_ = {q4[T][0], q4[T][1], q4[T][2], q4[T][3]};            \
        *(f32x4*)((OUTP) + ((I) - 3)) = v_;                                   \
    }                                                                         \
} while (0)

// pair P: o0 = 2P, o1 = 2P+1. One barrier per pair; acc strictly scoped
// within the pair (no cross-barrier register carry).
#define RBF_PAIR(P) do {                                                      \
    __syncthreads();                                                          \
    if ((P) < 15) { RBF_STAGE(2 * (P) + 2); RBF_STAGE(2 * (P) + 3); }         \
    {                                                                         \
        const char* b0_ = (const char*)&sA[(2 * (P)) & 3][0];                 \
        bf16x8 g_[8];                                                         \
        RBF_READS(g_, b0_);                                                   \
        f32x16 A0_, A1_, B0_, B1_;                                            \
        RBF_MFMA2(g_, A0_, A1_, B0_, B1_);                                    \
        const char* b1_ = (const char*)&sA[(2 * (P) + 1) & 3][0];             \
        RBF_READS(g_, b1_);            /* o1 reads issue under o0 dots */     \
        RBF_DOT(A0_, A1_, 2 * (P), 0, outp0);                                 \
        RBF_DOT(B0_, B1_, 2 * (P), 1, outp1);                                 \
        RBF_MFMA2(g_, A0_, A1_, B0_, B1_);                                    \
        RBF_DOT(A0_, A1_, 2 * (P) + 1, 0, outp0);                             \
        RBF_DOT(B0_, B1_, 2 * (P) + 1, 1, outp1);                             \
    }                                                                         \
} while (0)

    RBF_PAIR(0);  RBF_PAIR(1);  RBF_PAIR(2);  RBF_PAIR(3);
    RBF_PAIR(4);  RBF_PAIR(5);  RBF_PAIR(6);  RBF_PAIR(7);
    RBF_PAIR(8);  RBF_PAIR(9);  RBF_PAIR(10); RBF_PAIR(11);
    RBF_PAIR(12); RBF_PAIR(13); RBF_PAIR(14); RBF_PAIR(15);

#undef RBF_PAIR
#undef RBF_DOT
#undef RBF_MFMA2
#undef RBF_READS
#undef RBF_STAGE
}

extern "C" void kernel_launch(void* const* d_in, const int* in_sizes, int n_in,
                              void* d_out, int out_size, void* d_ws, size_t ws_size,
                              hipStream_t stream)
{
    const float* x = (const float*)d_in[0];
    const float* means = (const float*)d_in[1];
    const float* inv = (const float*)d_in[2];
    float* out = (float*)d_out;

    char* w = (char*)d_ws;
    __bf16* Atp  = (__bf16*)w;                                     // 16.78 MB
    __bf16* cPhi = (__bf16*)(w + (size_t)O_N * 4096 * 2);          // 256 KB
    __bf16* cPlo = (__bf16*)(w + (size_t)O_N * 4096 * 2 + 262144); // 256 KB
    float*  kArr = (float*)(w + (size_t)O_N * 4096 * 2 + 524288);  // 8 KB

    rbf_prep<<<dim3(O_N), dim3(256), 0, stream>>>(inv, means, Atp, cPhi, cPlo, kArr);
    rbf_main<<<dim3(1024), dim3(128), 0, stream>>>(x, Atp, cPhi, cPlo, kArr, out);

    (void)in_sizes; (void)n_in; (void)out_size; (void)ws_size;
}

// Round 10
// 60.792 us; speedup vs baseline: 1.3906x; 1.0420x over previous
//
#include <hip/hip_runtime.h>
#include <hip/hip_bf16.h>

typedef __bf16 bf16x8 __attribute__((ext_vector_type(8)));
typedef float f32x16 __attribute__((ext_vector_type(16)));

#define B_N 2048
#define O_N 2048
#define K_TRI 2080
#define K_TOT 2304
#define K_STEPS 36

__device__ __forceinline__ void gld16(const void* g, void* l) {
    __builtin_amdgcn_global_load_lds(
        (const __attribute__((address_space(1))) void*)g,
        (__attribute__((address_space(3))) void*)l,
        16, 0, 0);
}

// ---------------------------------------------------------------------------
// prep2: blocks [0,2048) build S rows (per o); [2048,4096) build P rows (b).
// Column layout (K_TOT=2304):
//   [0,2080)      tri-packed quadratic: S: A_ij+A_ji (i<j) / A_ii ; P: x_i*x_j
//   [2080,2144)   S: c_hi   P: x_hi          (c = -(A^T m + A m))
//   [2144,2208)   S: c_hi   P: x_lo
//   [2208,2272)   S: c_lo   P: x_hi
//   [2272,2274)   S: k_hi,k_lo  P: 1,1       (k = m^T A m)
//   [2274,2304)   zeros (pad to 36*64)
// q[b,o] = sum_k P[b,k]*S[o,k];  out = exp(-q/2) via GEMM + exp2 epilogue.
// ---------------------------------------------------------------------------
__global__ __launch_bounds__(256) void rbf_prep2(
    const float* __restrict__ inv, const float* __restrict__ means,
    const float* __restrict__ x, __bf16* __restrict__ S, __bf16* __restrict__ P)
{
    __shared__ float s[64 * 65];
    __shared__ float mld[64];
    __shared__ float uw[128];
    __shared__ unsigned short ptab[K_TRI];

    const int t = threadIdx.x;
    // pair table: p -> (i<<8)|j, i<=j, row-major upper triangle
    {
        int base = 0;
#pragma unroll 1
        for (int i = 0; i < 64; ++i) {
            if (t < 64 - i) ptab[base + t] = (unsigned short)((i << 8) | (i + t));
            base += 64 - i;
        }
    }

    if ((int)blockIdx.x < O_N) {
        const int o = blockIdx.x;
        const float4* src = (const float4*)(inv + (size_t)o * 4096);
#pragma unroll
        for (int k = 0; k < 4; ++k) {
            const int idx = k * 256 + t;
            const float4 v = src[idx];
            const int i = idx >> 4;
            const int j0 = (idx & 15) * 4;
            s[i * 65 + j0 + 0] = v.x * v.x;
            s[i * 65 + j0 + 1] = v.y * v.y;
            s[i * 65 + j0 + 2] = v.z * v.z;
            s[i * 65 + j0 + 3] = v.w * v.w;
        }
        if (t < 64) mld[t] = means[(size_t)t * O_N + o];
        __syncthreads();
        if (t < 64) {                 // u_j = sum_i A[i][j] m_i
            float u = 0.f;
#pragma unroll
            for (int i = 0; i < 64; ++i) u = fmaf(s[i * 65 + t], mld[i], u);
            uw[t] = u;
        } else if (t < 128) {         // w_j = sum_i A[j][i] m_i
            const int j = t - 64;
            float w = 0.f;
#pragma unroll
            for (int i = 0; i < 64; ++i) w = fmaf(s[j * 65 + i], mld[i], w);
            uw[64 + j] = w;
        }
        __syncthreads();
        __bf16* Srow = S + (size_t)o * K_TOT;
#pragma unroll 1
        for (int p = t; p < K_TRI; p += 256) {
            const int ij = ptab[p];
            const int i = ij >> 8, j = ij & 255;
            const float v = (i == j) ? s[i * 65 + i]
                                     : (s[i * 65 + j] + s[j * 65 + i]);
            Srow[p] = (__bf16)v;
        }
        if (t < 64) {
            const float c = -(uw[t] + uw[64 + t]);
            const __bf16 hi = (__bf16)c;
            const __bf16 lo = (__bf16)(c - (float)hi);
            Srow[K_TRI + t] = hi;
            Srow[K_TRI + 64 + t] = hi;
            Srow[K_TRI + 128 + t] = lo;
        }
        if (t == 0) {
            float kk = 0.f;
#pragma unroll
            for (int j = 0; j < 64; ++j) kk = fmaf(uw[j], mld[j], kk);
            const __bf16 khi = (__bf16)kk;
            const __bf16 klo = (__bf16)(kk - (float)khi);
            Srow[2272] = khi;
            Srow[2273] = klo;
        }
        if (t < K_TOT - 2274) Srow[2274 + t] = (__bf16)0.f;
    } else {
        const int b = (int)blockIdx.x - O_N;
        if (t < 64) mld[t] = x[(size_t)b * 64 + t];   // reuse mld as x-row
        __syncthreads();
        __bf16* Prow = P + (size_t)b * K_TOT;
#pragma unroll 1
        for (int p = t; p < K_TRI; p += 256) {
            const int ij = ptab[p];
            Prow[p] = (__bf16)(mld[ij >> 8] * mld[ij & 255]);
        }
        if (t < 64) {
            const float v = mld[t];
            const __bf16 hi = (__bf16)v;
            Prow[K_TRI + t] = hi;
            Prow[K_TRI + 64 + t] = (__bf16)(v - (float)hi);
            Prow[K_TRI + 128 + t] = hi;
        }
        if (t == 0) {
            Prow[2272] = (__bf16)1.f;
            Prow[2273] = (__bf16)1.f;
        }
        if (t < K_TOT - 2274) Prow[2274 + t] = (__bf16)0.f;
    }
}

// ---------------------------------------------------------------------------
// main GEMM: C[64b x 64o] per block, grid 1024 = 8 XCD x (4 o-blk x 32 b-blk)
// -> 4 blocks/CU, 16 waves/CU. Per K=64 step: stage P-tile 8KB + S-tile 8KB
// (gld16, linear dest, inverse-swizzled source), each wave 8 x ds_read_b128
// (XOR-swizzled, conflict-free) + 4 MFMA into 2 independent acc chains.
// Epilogue: out = exp2(-acc * log2(e)/2). No per-o tail in the loop.
// A-frag: lane&31 = b-row; B-frag: lane&31 = o-col; k = (lane>>5)*8+e.
// C: col = lane&31, row = (r&3)+8*(r>>2)+4*(lane>>5).
// ---------------------------------------------------------------------------
__global__ __launch_bounds__(256, 4) void rbf_gemm(
    const __bf16* __restrict__ P, const __bf16* __restrict__ S,
    float* __restrict__ out)
{
    __shared__ __align__(16) char sP[2][8192];
    __shared__ __align__(16) char sS[2][8192];

    const int tid = threadIdx.x;
    const int lane = tid & 63;
    const int w = tid >> 6;
    const int wr = w >> 1, wc = w & 1;
    const int cl = lane & 31;
    const int h = lane >> 5;

    const int wg = (int)blockIdx.x;
    const int xcd = wg & 7;
    const int loc = wg >> 3;            // 0..127
    const int ogl = loc & 3;            // 4 o-blocks per XCD strip (L2 slice)
    const int bg = loc >> 2;            // 0..31
    const int oBase = (xcd * 4 + ogl) * 64;
    const int bBase = bg * 64;

    // staging: thread t owns LDS bytes [t*16) and [4096+t*16) of each tile.
    // LDS byte L <- global row(L)=L>>7, col=(L&127)^((row&7)<<4)  (involution)
    const int L0 = tid * 16, L1 = 4096 + tid * 16;
    const int r0 = L0 >> 7, r1 = L1 >> 7;
    const int c0 = (L0 & 127) ^ ((r0 & 7) << 4);
    const int c1 = (L1 & 127) ^ ((r1 & 7) << 4);
    const char* gP0 = (const char*)P + (size_t)(bBase + r0) * (K_TOT * 2) + c0;
    const char* gP1 = (const char*)P + (size_t)(bBase + r1) * (K_TOT * 2) + c1;
    const char* gS0 = (const char*)S + (size_t)(oBase + r0) * (K_TOT * 2) + c0;
    const char* gS1 = (const char*)S + (size_t)(oBase + r1) * (K_TOT * 2) + c1;

    // frag read bases (swizzled reads within the row)
    const int arow = wr * 32 + cl;
    const int brow = wc * 32 + cl;
    const char* aPb = &sP[0][0] + arow * 128;
    const char* aSb = &sS[0][0] + brow * 128;
    const int mA = (arow & 7) << 4;
    const int mB = (brow & 7) << 4;

    // prologue: stage step 0 into buffer 0
    gld16(gP0, &sP[0][0] + L0);
    gld16(gP1, &sP[0][0] + L1);
    gld16(gS0, &sS[0][0] + L0);
    gld16(gS1, &sS[0][0] + L1);

    const f32x16 zz = {0.f,0.f,0.f,0.f,0.f,0.f,0.f,0.f,
                       0.f,0.f,0.f,0.f,0.f,0.f,0.f,0.f};
    f32x16 acc0 = zz, acc1 = zz;

#pragma unroll 2
    for (int st = 0; st < K_STEPS; ++st) {
        __syncthreads();
        if (st < K_STEPS - 1) {
            const int nb = (st + 1) & 1;
            const size_t go = (size_t)(st + 1) * 128;
            gld16(gP0 + go, &sP[nb][0] + L0);
            gld16(gP1 + go, &sP[nb][0] + L1);
            gld16(gS0 + go, &sS[nb][0] + L0);
            gld16(gS1 + go, &sS[nb][0] + L1);
        }
        const int bo = (st & 1) * 8192;
        const bf16x8 a0 = *(const bf16x8*)(aPb + bo + ((0  + h * 16) ^ mA));
        const bf16x8 b0 = *(const bf16x8*)(aSb + bo + ((0  + h * 16) ^ mB));
        const bf16x8 a1 = *(const bf16x8*)(aPb + bo + ((32 + h * 16) ^ mA));
        const bf16x8 b1 = *(const bf16x8*)(aSb + bo + ((32 + h * 16) ^ mB));
        const bf16x8 a2 = *(const bf16x8*)(aPb + bo + ((64 + h * 16) ^ mA));
        const bf16x8 b2 = *(const bf16x8*)(aSb + bo + ((64 + h * 16) ^ mB));
        const bf16x8 a3 = *(const bf16x8*)(aPb + bo + ((96 + h * 16) ^ mA));
        const bf16x8 b3 = *(const bf16x8*)(aSb + bo + ((96 + h * 16) ^ mB));
        __builtin_amdgcn_s_setprio(1);
        acc0 = __builtin_amdgcn_mfma_f32_32x32x16_bf16(a0, b0, acc0, 0, 0, 0);
        acc1 = __builtin_amdgcn_mfma_f32_32x32x16_bf16(a1, b1, acc1, 0, 0, 0);
        acc0 = __builtin_amdgcn_mfma_f32_32x32x16_bf16(a2, b2, acc0, 0, 0, 0);
        acc1 = __builtin_amdgcn_mfma_f32_32x32x16_bf16(a3, b3, acc1, 0, 0, 0);
        __builtin_amdgcn_s_setprio(0);
    }

    const f32x16 accv = acc0 + acc1;
#pragma unroll
    for (int r = 0; r < 16; ++r) {
        const int row = (r & 3) + 8 * (r >> 2) + 4 * h;
        out[(size_t)(bBase + wr * 32 + row) * O_N + oBase + wc * 32 + cl] =
            exp2f(accv[r] * -0.72134752044448170368f);   // exp(-q/2)
    }
}

extern "C" void kernel_launch(void* const* d_in, const int* in_sizes, int n_in,
                              void* d_out, int out_size, void* d_ws, size_t ws_size,
                              hipStream_t stream)
{
    const float* x = (const float*)d_in[0];
    const float* means = (const float*)d_in[1];
    const float* inv = (const float*)d_in[2];
    float* out = (float*)d_out;

    // workspace: S rows 9.44 MB | P rows 9.44 MB   (total ~18.9 MB)
    __bf16* S = (__bf16*)d_ws;
    __bf16* P = (__bf16*)((char*)d_ws + (size_t)O_N * K_TOT * sizeof(__bf16));

    rbf_prep2<<<dim3(2 * O_N), dim3(256), 0, stream>>>(inv, means, x, S, P);
    rbf_gemm<<<dim3(1024), dim3(256), 0, stream>>>(P, S, out);

    (void)in_sizes; (void)n_in; (void)out_size; (void)ws_size;
}